// Round 7
// baseline (857.323 us; speedup 1.0000x reference)
//
#include <hip/hip_runtime.h>
#include <math.h>

// ============================================================================
// CapsuleNet forward, round 7.
// prim MFMA: BM=64 x BN=256 (nb=1 -> each A byte read ONCE), split-K 4
//   (1152 blocks = 4.5/CU, all co-resident), ks-per-XCD swizzle so each XCD's
//   L2 holds one 2.65 MB B slice; XOR-swizzled conflict-free staging (R6).
// squash: 4-slice reduce, cc-fastest contiguous reads.
// conv1, wtrans, priors (R6 register version), routing, classes, fc as R6.
// ============================================================================

typedef _Float16 f16;
typedef _Float16 f16x8 __attribute__((ext_vector_type(8)));
typedef _Float16 f16x4 __attribute__((ext_vector_type(4)));
typedef float f32x4 __attribute__((ext_vector_type(4)));

__device__ __forceinline__ void gl_lds16(const void* g, void* l) {
  __builtin_amdgcn_global_load_lds(
      (const __attribute__((address_space(1))) void*)g,
      (__attribute__((address_space(3))) void*)l, 16, 0, 0);
}

// ---------------- conv1: x[512,1,28,28] -> ht fp16 NHWC [512,20,20,256] ----
__global__ __launch_bounds__(256, 2) void conv1_kernel(
    const float* __restrict__ x, const float* __restrict__ w,
    const float* __restrict__ bias, f16* __restrict__ ht)
{
  __shared__ float xs[784];
  const int b = blockIdx.x;
  const int t = threadIdx.x;          // t == output channel (ic of ht)
  for (int i = t; i < 784; i += 256) xs[i] = x[b * 784 + i];
  float wr[81];
#pragma unroll
  for (int k = 0; k < 81; ++k) wr[k] = w[t * 81 + k];
  const float bv = bias[t];
  __syncthreads();
  for (int oy = 0; oy < 20; ++oy) {
    float acc[20];
#pragma unroll
    for (int i = 0; i < 20; ++i) acc[i] = bv;
#pragma unroll
    for (int ky = 0; ky < 9; ++ky) {
      float xr[28];
#pragma unroll
      for (int q = 0; q < 7; ++q) {
        const float4 v = *(const float4*)&xs[(oy + ky) * 28 + q * 4];
        xr[q*4+0] = v.x; xr[q*4+1] = v.y; xr[q*4+2] = v.z; xr[q*4+3] = v.w;
      }
#pragma unroll
      for (int kx = 0; kx < 9; ++kx) {
        const float wv = wr[ky * 9 + kx];
#pragma unroll
        for (int ox = 0; ox < 20; ++ox) acc[ox] = fmaf(xr[ox + kx], wv, acc[ox]);
      }
    }
    f16* hp = &ht[(size_t)((b * 20 + oy) * 20) * 256 + t];
#pragma unroll
    for (int ox = 0; ox < 20; ++ox)
      hp[ox * 256] = (f16)fmaxf(acc[ox], 0.f);
  }
}

// --------- wtrans: prim_w fp32 [oc][ic][kykx] -> wt fp16 [oc][kykx][ic] ----
__global__ __launch_bounds__(256) void wtrans_kernel(
    const float* __restrict__ w, f16* __restrict__ wt)
{
  __shared__ float tile[64 * 83];
  const int oc = blockIdx.x;
  const int icq = blockIdx.y;
  const int t = threadIdx.x;
  const float* src = w + (size_t)oc * 20736 + (size_t)icq * 64 * 81;
  for (int idx = t; idx < 5184; idx += 256) {
    const int ici = idx / 81, kk = idx - ici * 81;
    tile[ici * 83 + kk] = src[idx];
  }
  __syncthreads();
  f16* dst = wt + (size_t)oc * 20736 + icq * 64;
  for (int idx = t; idx < 5184; idx += 256) {
    const int kk = idx >> 6, ici = idx & 63;
    dst[kk * 256 + ici] = (f16)tile[ici * 83 + kk];
  }
}

// ---------------- primary caps conv: MFMA implicit GEMM --------------------
// 1152 blocks: ks = (id&7)>>1 (one ks per XCD under round-robin dispatch ->
// its 2.65 MB B-quarter stays L2-resident), mb = (id>>3)*2 + (id&1), 288 mb.
// Block tile 64(m) x 256(n), 4 waves side-by-side in n; wave tile 64x64.
// A staged once globally (nb=1). XOR-swizzled chunk staging = conflict-free.
__global__ __launch_bounds__(256) void prim_mfma_kernel(
    const f16* __restrict__ ht, const f16* __restrict__ wt,
    float* __restrict__ part)
{
  __shared__ f16 sm[10240];           // As 64x32 (4KB) | Bs 256x32 (16KB)
  f16* As = sm;
  f16* Bs = sm + 2048;
  const int t = threadIdx.x;
  const int wv = t >> 6, lane = t & 63;
  const int id = blockIdx.x;
  const int ks = (id & 7) >> 1;
  const int mb = ((id >> 3) << 1) | (id & 1);
  const int m0 = mb * 64;

  const int chunk = (lane & 3) ^ ((lane >> 3) & 3);
  long aoff;
  {
    const int r = wv * 16 + (lane >> 2);
    const int m = m0 + r;
    const int b = m / 36, pos = m - b * 36;
    const int oy = pos / 6, ox = pos - oy * 6;
    aoff = (long)(((b * 20 + 2 * oy) * 20 + 2 * ox) * 256) * 2 + chunk * 16;
  }
  long boff[4];
#pragma unroll
  for (int i = 0; i < 4; ++i) {
    const int r = i * 64 + wv * 16 + (lane >> 2);   // r == oc
    boff[i] = (long)r * 41472 + chunk * 16;         // oc*81*256*2
  }
  const char* htc = (const char*)ht;
  const char* wtc = (const char*)wt;

  const int lrow = lane & 15, quad = lane >> 4;
  const int qx = quad ^ ((lrow >> 1) & 3);
  f32x4 acc[4][4] = {};

  const int s0 = ks * 162, s1 = s0 + 162;   // 648 BK=32 stages over 4 ks
  for (int s = s0; s < s1; ++s) {
    const int kykx = s >> 3, icb = s & 7;
    const int ky = kykx / 9, kx = kykx - ky * 9;
    const long astep = (long)((((ky * 20 + kx) * 256) + icb * 32) * 2);
    const long bstep = (long)(((kykx * 256) + icb * 32) * 2);
    __syncthreads();
    {
      gl_lds16(htc + aoff + astep, (char*)As + wv * 1024);
#pragma unroll
      for (int i = 0; i < 4; ++i)
        gl_lds16(wtc + boff[i] + bstep, (char*)Bs + i * 4096 + wv * 1024);
    }
    __syncthreads();
    f16x8 af[4], bf[4];
#pragma unroll
    for (int mt = 0; mt < 4; ++mt)
      af[mt] = *(const f16x8*)&As[(mt * 16 + lrow) * 32 + qx * 8];
#pragma unroll
    for (int nt = 0; nt < 4; ++nt)
      bf[nt] = *(const f16x8*)&Bs[(wv * 64 + nt * 16 + lrow) * 32 + qx * 8];
#pragma unroll
    for (int mt = 0; mt < 4; ++mt)
#pragma unroll
      for (int nt = 0; nt < 4; ++nt)
        acc[mt][nt] = __builtin_amdgcn_mfma_f32_16x16x32_f16(
            af[mt], bf[nt], acc[mt][nt], 0, 0, 0);
  }

  // epilogue: partials [m][col'] with col' = (oc&31)*8 + oc>>5 (squash reads
  // its 8 values oc = i*32+cc contiguously).
  float* pp = part + (size_t)ks * 4718592;
#pragma unroll
  for (int mt = 0; mt < 4; ++mt) {
    const int mbase = m0 + mt * 16 + quad * 4;            // row=quad*4+reg
#pragma unroll
    for (int nt = 0; nt < 4; ++nt) {
      const int n = wv * 64 + nt * 16 + lrow;             // col=lane&15
      const int np = (n & 31) * 8 + (n >> 5);
#pragma unroll
      for (int rg = 0; rg < 4; ++rg)
        pp[(size_t)(mbase + rg) * 256 + np] = acc[mt][nt][rg];
    }
  }
}

// --------- split-K(4) reduce + bias + squash -> u[512,1152,8] fp32 ---------
__global__ void squash_kernel(const float* __restrict__ part,
                              const float* __restrict__ bias,
                              float* __restrict__ u)
{
  const int tid = blockIdx.x * 256 + threadIdx.x;   // (b*36+pos)*32 + cc
  if (tid >= 512 * 36 * 32) return;
  const int cc = tid & 31;
  const int row = tid >> 5;                         // b*36 + pos
  const int b = row / 36;
  const int pos = row - b * 36;
  const float* p = part + (size_t)row * 256 + cc * 8;
  float v[8] = {};
#pragma unroll
  for (int ksl = 0; ksl < 4; ++ksl) {
    const float4 a0 = *(const float4*)(p + (size_t)ksl * 4718592);
    const float4 a1 = *(const float4*)(p + (size_t)ksl * 4718592 + 4);
    v[0] += a0.x; v[1] += a0.y; v[2] += a0.z; v[3] += a0.w;
    v[4] += a1.x; v[5] += a1.y; v[6] += a1.z; v[7] += a1.w;
  }
  float sq = 0.f;
#pragma unroll
  for (int i = 0; i < 8; ++i) {
    v[i] += bias[i * 32 + cc];
    sq = fmaf(v[i], v[i], sq);
  }
  const float scale = sq / ((1.f + sq) * sqrtf(sq));
  float* up = &u[(size_t)(b * 1152 + cc * 36 + pos) * 8];
#pragma unroll
  for (int i = 0; i < 8; ++i) up[i] = v[i] * scale;
}

// --------- priors: P[c,b,r,16] fp16 = einsum('bri,crio') -------------------
// grid (18 r-chunks, 8 b-chunks, 10 c). Thread (rl=t>>2, oq=t&3) holds
// rw[c][r][*][oq*4..+4] in 32 registers; loops 64 b; 512B/wave stores.
__global__ __launch_bounds__(256, 4) void priors_kernel(
    const float* __restrict__ u, const float* __restrict__ rw,
    f16* __restrict__ P)
{
  const int t = threadIdx.x;
  const int rl = t >> 2, oq = t & 3;
  const int r = blockIdx.x * 64 + rl;
  const int b0 = blockIdx.y * 64;
  const int c = blockIdx.z;

  float4 wreg[8];
  const float* wbase = rw + (size_t)(c * 1152 + r) * 128 + oq * 4;
#pragma unroll
  for (int k = 0; k < 8; ++k)
    wreg[k] = *(const float4*)(wbase + k * 16);

  f16* pbase = P + (size_t)((c * 512 + b0) * 1152 + r) * 16 + oq * 4;
  const float* ubase = u + (size_t)(b0 * 1152 + r) * 8;

  for (int b = 0; b < 64; ++b) {
    const float4 ua = *(const float4*)(ubase + (size_t)b * 9216);
    const float4 ub = *(const float4*)(ubase + (size_t)b * 9216 + 4);
    const float uu[8] = {ua.x, ua.y, ua.z, ua.w, ub.x, ub.y, ub.z, ub.w};
    float ax = 0.f, ay = 0.f, az = 0.f, aw = 0.f;
#pragma unroll
    for (int k = 0; k < 8; ++k) {
      ax = fmaf(uu[k], wreg[k].x, ax);
      ay = fmaf(uu[k], wreg[k].y, ay);
      az = fmaf(uu[k], wreg[k].z, az);
      aw = fmaf(uu[k], wreg[k].w, aw);
    }
    f16x4 st;
    st[0] = (f16)ax; st[1] = (f16)ay; st[2] = (f16)az; st[3] = (f16)aw;
    *(f16x4*)(pbase + (size_t)b * 18432) = st;
  }
}

// ---------------- dynamic routing, one block per (c,b) ---------------------
__device__ __forceinline__ float wave_sum(float v) {
#pragma unroll
  for (int off = 32; off > 0; off >>= 1) v += __shfl_xor(v, off);
  return v;
}
__device__ __forceinline__ float wave_max(float v) {
#pragma unroll
  for (int off = 32; off > 0; off >>= 1) v = fmaxf(v, __shfl_xor(v, off));
  return v;
}

__global__ __launch_bounds__(256, 2) void routing_kernel(
    const f16* __restrict__ Pg, float* __restrict__ caps)
{
  const int c = blockIdx.x >> 9;
  const int b = blockIdx.x & 511;
  const int t = threadIdx.x;
  const int wid = t >> 6;
  const int lane = t & 63;
  __shared__ float xred[4 * 17];

  float P[5][16];
  float lg[5];
  const int nk = (t < 128) ? 5 : 4;
#pragma unroll
  for (int k = 0; k < 5; ++k)
#pragma unroll
    for (int o = 0; o < 16; ++o) P[k][o] = 0.f;

  const f16* pbase = Pg + (size_t)((c * 512 + b) * 1152) * 16;
#pragma unroll
  for (int k = 0; k < 5; ++k) {
    if (k < nk) {
      const int r = t + (k << 8);
      const f16x8 p0 = *(const f16x8*)&pbase[(size_t)r * 16];
      const f16x8 p1 = *(const f16x8*)&pbase[(size_t)r * 16 + 8];
#pragma unroll
      for (int o = 0; o < 8; ++o) {
        P[k][o]     = (float)p0[o];
        P[k][o + 8] = (float)p1[o];
      }
    }
  }

  float v[16];
  {
    float sq = 0.f;
#pragma unroll
    for (int o = 0; o < 16; ++o) {
      float p = 0.f;
#pragma unroll
      for (int k = 0; k < 5; ++k) p += P[k][o];
      p = wave_sum(p);
      if (lane == 0) xred[wid * 17 + o] = p;
      v[o] = 0.f;
    }
    __syncthreads();
#pragma unroll
    for (int o = 0; o < 16; ++o) {
      const float s = (xred[o] + xred[17 + o] + xred[34 + o] + xred[51 + o]) *
                      (1.f / 1152.f);
      v[o] = s;
      sq = fmaf(s, s, sq);
    }
    const float scale = sq / ((1.f + sq) * sqrtf(sq));
#pragma unroll
    for (int o = 0; o < 16; ++o) v[o] *= scale;
    __syncthreads();
  }
#pragma unroll
  for (int k = 0; k < 5; ++k) {
    float a = 0.f;
#pragma unroll
    for (int o = 0; o < 16; ++o) a = fmaf(P[k][o], v[o], a);
    lg[k] = a;
  }

  for (int it = 1; it < 3; ++it) {
    float m = -1e30f;
#pragma unroll
    for (int k = 0; k < 5; ++k) if (k < nk) m = fmaxf(m, lg[k]);
    m = wave_max(m);
    if (lane == 0) xred[wid * 17 + 16] = m;
    __syncthreads();
    const float mx = fmaxf(fmaxf(xred[16], xred[17 + 16]),
                           fmaxf(xred[34 + 16], xred[51 + 16]));
    __syncthreads();
    float e[5];
#pragma unroll
    for (int k = 0; k < 5; ++k) e[k] = (k < nk) ? expf(lg[k] - mx) : 0.f;
    float pS = 0.f;
#pragma unroll
    for (int k = 0; k < 5; ++k) pS += e[k];
    pS = wave_sum(pS);
    if (lane == 0) xred[wid * 17 + 16] = pS;
#pragma unroll
    for (int o = 0; o < 16; ++o) {
      float p = 0.f;
#pragma unroll
      for (int k = 0; k < 5; ++k) p = fmaf(e[k], P[k][o], p);
      p = wave_sum(p);
      if (lane == 0) xred[wid * 17 + o] = p;
    }
    __syncthreads();
    const float S = xred[16] + xred[17 + 16] + xred[34 + 16] + xred[51 + 16];
    const float inv = 1.f / S;
    float sq = 0.f;
#pragma unroll
    for (int o = 0; o < 16; ++o) {
      const float s = (xred[o] + xred[17 + o] + xred[34 + o] + xred[51 + o]) * inv;
      v[o] = s;
      sq = fmaf(s, s, sq);
    }
    const float scale = sq / ((1.f + sq) * sqrtf(sq));
#pragma unroll
    for (int o = 0; o < 16; ++o) v[o] *= scale;
    __syncthreads();
    if (it < 2) {
#pragma unroll
      for (int k = 0; k < 5; ++k) {
        float a = 0.f;
#pragma unroll
        for (int o = 0; o < 16; ++o) a = fmaf(P[k][o], v[o], a);
        lg[k] += a;
      }
    }
  }
  if (t == 0) {
    float* cp = &caps[(b * 10 + c) * 16];
#pragma unroll
    for (int o = 0; o < 16; ++o) cp[o] = v[o];
  }
}

// --------- classes softmax + argmax one-hot mask ---------------------------
__global__ void classes_kernel(const float* __restrict__ caps,
                               float* __restrict__ out_classes,
                               float* __restrict__ d0)
{
  const int b = blockIdx.x * 256 + threadIdx.x;
  if (b >= 512) return;
  float nrm[10];
#pragma unroll
  for (int cc = 0; cc < 10; ++cc) {
    float sq = 0.f;
#pragma unroll
    for (int o = 0; o < 16; ++o) {
      const float vv = caps[(b * 10 + cc) * 16 + o];
      sq = fmaf(vv, vv, sq);
    }
    nrm[cc] = sqrtf(sq);
  }
  float mx = nrm[0]; int cs = 0;
#pragma unroll
  for (int cc = 1; cc < 10; ++cc)
    if (nrm[cc] > mx) { mx = nrm[cc]; cs = cc; }
  float e[10], ssum = 0.f;
#pragma unroll
  for (int cc = 0; cc < 10; ++cc) { e[cc] = expf(nrm[cc] - mx); ssum += e[cc]; }
  const float inv = 1.f / ssum;
#pragma unroll
  for (int cc = 0; cc < 10; ++cc) out_classes[b * 10 + cc] = e[cc] * inv;
#pragma unroll
  for (int cc = 0; cc < 10; ++cc)
#pragma unroll
    for (int o = 0; o < 16; ++o)
      d0[b * 160 + cc * 16 + o] = (cc == cs) ? caps[(b * 10 + cc) * 16 + o] : 0.f;
}

// --------- decoder GEMM: C[M,N] = act(A[M,K] @ W[N,K]^T + bias) ------------
__global__ __launch_bounds__(256, 2) void fc_kernel(
    const float* __restrict__ A, const float* __restrict__ W,
    const float* __restrict__ bias, float* __restrict__ C,
    int N, int K, int act)
{
  __shared__ float As[64][17];
  __shared__ float Ws[64][17];
  const int t = threadIdx.x;
  const int tm = t >> 4, tn = t & 15;
  const int m0 = blockIdx.y << 6, n0 = blockIdx.x << 6;
  const int lr = t >> 2, lq = (t & 3) << 2;
  float acc[4][4] = {};
  for (int k0 = 0; k0 < K; k0 += 16) {
    const float4 av = *(const float4*)&A[(m0 + lr) * K + k0 + lq];
    float4 wv = make_float4(0.f, 0.f, 0.f, 0.f);
    const int wn = n0 + lr;
    if (wn < N) wv = *(const float4*)&W[wn * K + k0 + lq];
    __syncthreads();
    As[lr][lq+0] = av.x; As[lr][lq+1] = av.y; As[lr][lq+2] = av.z; As[lr][lq+3] = av.w;
    Ws[lr][lq+0] = wv.x; Ws[lr][lq+1] = wv.y; Ws[lr][lq+2] = wv.z; Ws[lr][lq+3] = wv.w;
    __syncthreads();
#pragma unroll
    for (int kk = 0; kk < 16; ++kk) {
      float a[4], w[4];
#pragma unroll
      for (int i = 0; i < 4; ++i) a[i] = As[tm * 4 + i][kk];
#pragma unroll
      for (int j = 0; j < 4; ++j) w[j] = Ws[tn * 4 + j][kk];
#pragma unroll
      for (int i = 0; i < 4; ++i)
#pragma unroll
        for (int j = 0; j < 4; ++j) acc[i][j] = fmaf(a[i], w[j], acc[i][j]);
    }
  }
#pragma unroll
  for (int i = 0; i < 4; ++i) {
    const int m = m0 + tm * 4 + i;
#pragma unroll
    for (int j = 0; j < 4; ++j) {
      const int n = n0 + tn * 4 + j;
      if (n < N) {
        float vv = acc[i][j] + bias[n];
        vv = act ? (1.f / (1.f + expf(-vv))) : fmaxf(vv, 0.f);
        C[m * N + n] = vv;
      }
    }
  }
}

// ============================================================================
extern "C" void kernel_launch(void* const* d_in, const int* in_sizes, int n_in,
                              void* d_out, int out_size, void* d_ws, size_t ws_size,
                              hipStream_t stream)
{
  const float* x       = (const float*)d_in[0];
  const float* conv1_w = (const float*)d_in[1];
  const float* conv1_b = (const float*)d_in[2];
  const float* prim_w  = (const float*)d_in[3];
  const float* prim_b  = (const float*)d_in[4];
  const float* route_w = (const float*)d_in[5];
  const float* dec_w1  = (const float*)d_in[6];
  const float* dec_b1  = (const float*)d_in[7];
  const float* dec_w2  = (const float*)d_in[8];
  const float* dec_b2  = (const float*)d_in[9];
  const float* dec_w3  = (const float*)d_in[10];
  const float* dec_b3  = (const float*)d_in[11];
  float* out = (float*)d_out;

  char* ws = (char*)d_ws;
  f16*   ht   = (f16*)(ws);                        // 104,857,600 B
  f16*   wtp  = (f16*)(ws + 104857600);            //  10,616,832 B
  float* part = (float*)(ws + 115474432);          //  75,497,472 B (4 slices)
  float* u    = (float*)(ws + 190971904);          //  18,874,368 B
  f16*   P    = (f16*)(ws);                        // 188,743,680 B (overlays)
  float* caps = (float*)(ws + 209846272);          // 327,680 B
  float* d0   = (float*)(ws + 210173952);          // 327,680 B
  float* d1   = (float*)(ws + 210501632);          // 1,048,576 B
  float* d2   = (float*)(ws + 211550208);          // 2,097,152 B

  hipLaunchKernelGGL(conv1_kernel, dim3(512), dim3(256), 0, stream,
                     x, conv1_w, conv1_b, ht);
  hipLaunchKernelGGL(wtrans_kernel, dim3(256, 4), dim3(256), 0, stream,
                     prim_w, wtp);
  hipLaunchKernelGGL(prim_mfma_kernel, dim3(1152), dim3(256), 0, stream,
                     ht, wtp, part);
  hipLaunchKernelGGL(squash_kernel, dim3(2304), dim3(256), 0, stream,
                     part, prim_b, u);
  hipLaunchKernelGGL(priors_kernel, dim3(18, 8, 10), dim3(256), 0, stream,
                     u, route_w, P);
  hipLaunchKernelGGL(routing_kernel, dim3(5120), dim3(256), 0, stream,
                     P, caps);
  hipLaunchKernelGGL(classes_kernel, dim3(2), dim3(256), 0, stream,
                     caps, out, d0);
  hipLaunchKernelGGL(fc_kernel, dim3(8, 8), dim3(256), 0, stream,
                     d0, dec_w1, dec_b1, d1, 512, 160, 0);
  hipLaunchKernelGGL(fc_kernel, dim3(16, 8), dim3(256), 0, stream,
                     d1, dec_w2, dec_b2, d2, 1024, 512, 0);
  hipLaunchKernelGGL(fc_kernel, dim3(13, 8), dim3(256), 0, stream,
                     d2, dec_w3, dec_b3, out + 5120, 784, 1024, 1);
}

// Round 8
// 841.524 us; speedup vs baseline: 1.0188x; 1.0188x over previous
//
#include <hip/hip_runtime.h>
#include <math.h>

// ============================================================================
// CapsuleNet forward, round 8.
// prim MFMA: back to 128x128 tile (R6), BK=64 (halves barrier count; 32KB LDS
//   single-buffered), split-K 4 (1152 blocks ~4.5/CU co-resident TLP).
//   XOR staging generalized to 8 chunks/row: store global chunk
//   (lane&7)^((lane>>3)&7), read chunk (h*4+quad)^(lrow&7) -> uniform bank
//   spread (R6's measured-zero-conflict pattern).
// squash: 4-slice reduce, cc-fastest contiguous reads (R7).
// conv1, wtrans, priors, routing, classes, fc unchanged.
// ============================================================================

typedef _Float16 f16;
typedef _Float16 f16x8 __attribute__((ext_vector_type(8)));
typedef _Float16 f16x4 __attribute__((ext_vector_type(4)));
typedef float f32x4 __attribute__((ext_vector_type(4)));

__device__ __forceinline__ void gl_lds16(const void* g, void* l) {
  __builtin_amdgcn_global_load_lds(
      (const __attribute__((address_space(1))) void*)g,
      (__attribute__((address_space(3))) void*)l, 16, 0, 0);
}

// ---------------- conv1: x[512,1,28,28] -> ht fp16 NHWC [512,20,20,256] ----
__global__ __launch_bounds__(256, 2) void conv1_kernel(
    const float* __restrict__ x, const float* __restrict__ w,
    const float* __restrict__ bias, f16* __restrict__ ht)
{
  __shared__ float xs[784];
  const int b = blockIdx.x;
  const int t = threadIdx.x;          // t == output channel (ic of ht)
  for (int i = t; i < 784; i += 256) xs[i] = x[b * 784 + i];
  float wr[81];
#pragma unroll
  for (int k = 0; k < 81; ++k) wr[k] = w[t * 81 + k];
  const float bv = bias[t];
  __syncthreads();
  for (int oy = 0; oy < 20; ++oy) {
    float acc[20];
#pragma unroll
    for (int i = 0; i < 20; ++i) acc[i] = bv;
#pragma unroll
    for (int ky = 0; ky < 9; ++ky) {
      float xr[28];
#pragma unroll
      for (int q = 0; q < 7; ++q) {
        const float4 v = *(const float4*)&xs[(oy + ky) * 28 + q * 4];
        xr[q*4+0] = v.x; xr[q*4+1] = v.y; xr[q*4+2] = v.z; xr[q*4+3] = v.w;
      }
#pragma unroll
      for (int kx = 0; kx < 9; ++kx) {
        const float wv = wr[ky * 9 + kx];
#pragma unroll
        for (int ox = 0; ox < 20; ++ox) acc[ox] = fmaf(xr[ox + kx], wv, acc[ox]);
      }
    }
    f16* hp = &ht[(size_t)((b * 20 + oy) * 20) * 256 + t];
#pragma unroll
    for (int ox = 0; ox < 20; ++ox)
      hp[ox * 256] = (f16)fmaxf(acc[ox], 0.f);
  }
}

// --------- wtrans: prim_w fp32 [oc][ic][kykx] -> wt fp16 [oc][kykx][ic] ----
__global__ __launch_bounds__(256) void wtrans_kernel(
    const float* __restrict__ w, f16* __restrict__ wt)
{
  __shared__ float tile[64 * 83];
  const int oc = blockIdx.x;
  const int icq = blockIdx.y;
  const int t = threadIdx.x;
  const float* src = w + (size_t)oc * 20736 + (size_t)icq * 64 * 81;
  for (int idx = t; idx < 5184; idx += 256) {
    const int ici = idx / 81, kk = idx - ici * 81;
    tile[ici * 83 + kk] = src[idx];
  }
  __syncthreads();
  f16* dst = wt + (size_t)oc * 20736 + icq * 64;
  for (int idx = t; idx < 5184; idx += 256) {
    const int kk = idx >> 6, ici = idx & 63;
    dst[kk * 256 + ici] = (f16)tile[ici * 83 + kk];
  }
}

// ---------------- primary caps conv: MFMA implicit GEMM --------------------
// 1152 blocks = 144 mb x 2 nb x 4 ks (id&7 = mb low bits -> siblings share
// an XCD L2). 4 waves, wave tile 64x64, BK=64: per stage each wave stages
// 32 A-rows + 32 B-rows (4+4 glds of 1KB) then runs 2 k-halves x 16 MFMA.
__global__ __launch_bounds__(256) void prim_mfma_kernel(
    const f16* __restrict__ ht, const f16* __restrict__ wt,
    float* __restrict__ part)
{
  __shared__ f16 sm[16384];           // As 128x64 | Bs 128x64, 32 KB
  const int t = threadIdx.x;
  const int wv = t >> 6, lane = t & 63;
  const int id = blockIdx.x;
  const int g = id >> 3;              // [0,144)
  const int ks = g & 3;
  const int nb = (g >> 2) & 1;
  const int mb = (id & 7) + 8 * (g >> 3);
  const int m0 = mb * 128, n0 = nb * 128;

  // lane stages global chunk (lane&7)^((lane>>3)&7) of row r0+(lane>>3);
  // slot (r, c') then holds global chunk c'^(r&7) -> consumer XOR undoes it.
  const int chunk = (lane & 7) ^ ((lane >> 3) & 7);
  long aoff[4], boff[4];
#pragma unroll
  for (int i = 0; i < 4; ++i) {
    const int r = wv * 32 + i * 8 + (lane >> 3);   // local row in tile
    const int m = m0 + r;
    const int b = m / 36, pos = m - b * 36;
    const int oy = pos / 6, ox = pos - oy * 6;
    aoff[i] = (long)(((b * 20 + 2 * oy) * 20 + 2 * ox) * 256) * 2 + chunk * 16;
    boff[i] = (long)(n0 + r) * 41472 + chunk * 16;   // oc*81*256*2
  }
  const char* htc = (const char*)ht;
  const char* wtc = (const char*)wt;

  const int lrow = lane & 15, quad = lane >> 4;
  const int wm = wv & 1, wn = wv >> 1;
  f32x4 acc[4][4] = {};

  const int s0 = ks * 81, s1 = s0 + 81;   // 324 BK=64 stages over 4 ks
  for (int s = s0; s < s1; ++s) {
    const int kykx = s >> 2, icb = s & 3;
    const int ky = kykx / 9, kx = kykx - ky * 9;
    const long astep = (long)((((ky * 20 + kx) * 256) + icb * 64) * 2);
    const long bstep = (long)(((kykx * 256) + icb * 64) * 2);
    __syncthreads();
    {
      char* dA = (char*)sm + wv * 4096;
      char* dB = (char*)sm + 16384 + wv * 4096;
#pragma unroll
      for (int i = 0; i < 4; ++i) {
        gl_lds16(htc + aoff[i] + astep, dA + i * 1024);
        gl_lds16(wtc + boff[i] + bstep, dB + i * 1024);
      }
    }
    __syncthreads();
    const f16* As = sm;
    const f16* Bs = sm + 8192;
#pragma unroll
    for (int h = 0; h < 2; ++h) {
      f16x8 af[4], bf[4];
      const int cbase = h * 4 + quad;
      const int cp = cbase ^ (lrow & 7);
#pragma unroll
      for (int mt = 0; mt < 4; ++mt)
        af[mt] = *(const f16x8*)&As[(wm * 64 + mt * 16 + lrow) * 64 + cp * 8];
#pragma unroll
      for (int nt = 0; nt < 4; ++nt)
        bf[nt] = *(const f16x8*)&Bs[(wn * 64 + nt * 16 + lrow) * 64 + cp * 8];
#pragma unroll
      for (int mt = 0; mt < 4; ++mt)
#pragma unroll
        for (int nt = 0; nt < 4; ++nt)
          acc[mt][nt] = __builtin_amdgcn_mfma_f32_16x16x32_f16(
              af[mt], bf[nt], acc[mt][nt], 0, 0, 0);
    }
  }

  // epilogue: partials [m][col'] with col' = (oc&31)*8 + oc>>5 (squash reads
  // its 8 values oc = i*32+cc contiguously).
  float* pp = part + (size_t)ks * 4718592;
#pragma unroll
  for (int mt = 0; mt < 4; ++mt) {
    const int mbase = m0 + wm * 64 + mt * 16 + quad * 4;  // row=quad*4+reg
#pragma unroll
    for (int nt = 0; nt < 4; ++nt) {
      const int n = n0 + wn * 64 + nt * 16 + lrow;        // col=lane&15
      const int np = (n & 31) * 8 + (n >> 5);
#pragma unroll
      for (int rg = 0; rg < 4; ++rg)
        pp[(size_t)(mbase + rg) * 256 + np] = acc[mt][nt][rg];
    }
  }
}

// --------- split-K(4) reduce + bias + squash -> u[512,1152,8] fp32 ---------
__global__ void squash_kernel(const float* __restrict__ part,
                              const float* __restrict__ bias,
                              float* __restrict__ u)
{
  const int tid = blockIdx.x * 256 + threadIdx.x;   // (b*36+pos)*32 + cc
  if (tid >= 512 * 36 * 32) return;
  const int cc = tid & 31;
  const int row = tid >> 5;                         // b*36 + pos
  const int b = row / 36;
  const int pos = row - b * 36;
  const float* p = part + (size_t)row * 256 + cc * 8;
  float v[8] = {};
#pragma unroll
  for (int ksl = 0; ksl < 4; ++ksl) {
    const float4 a0 = *(const float4*)(p + (size_t)ksl * 4718592);
    const float4 a1 = *(const float4*)(p + (size_t)ksl * 4718592 + 4);
    v[0] += a0.x; v[1] += a0.y; v[2] += a0.z; v[3] += a0.w;
    v[4] += a1.x; v[5] += a1.y; v[6] += a1.z; v[7] += a1.w;
  }
  float sq = 0.f;
#pragma unroll
  for (int i = 0; i < 8; ++i) {
    v[i] += bias[i * 32 + cc];
    sq = fmaf(v[i], v[i], sq);
  }
  const float scale = sq / ((1.f + sq) * sqrtf(sq));
  float* up = &u[(size_t)(b * 1152 + cc * 36 + pos) * 8];
#pragma unroll
  for (int i = 0; i < 8; ++i) up[i] = v[i] * scale;
}

// --------- priors: P[c,b,r,16] fp16 = einsum('bri,crio') -------------------
__global__ __launch_bounds__(256, 4) void priors_kernel(
    const float* __restrict__ u, const float* __restrict__ rw,
    f16* __restrict__ P)
{
  const int t = threadIdx.x;
  const int rl = t >> 2, oq = t & 3;
  const int r = blockIdx.x * 64 + rl;
  const int b0 = blockIdx.y * 64;
  const int c = blockIdx.z;

  float4 wreg[8];
  const float* wbase = rw + (size_t)(c * 1152 + r) * 128 + oq * 4;
#pragma unroll
  for (int k = 0; k < 8; ++k)
    wreg[k] = *(const float4*)(wbase + k * 16);

  f16* pbase = P + (size_t)((c * 512 + b0) * 1152 + r) * 16 + oq * 4;
  const float* ubase = u + (size_t)(b0 * 1152 + r) * 8;

  for (int b = 0; b < 64; ++b) {
    const float4 ua = *(const float4*)(ubase + (size_t)b * 9216);
    const float4 ub = *(const float4*)(ubase + (size_t)b * 9216 + 4);
    const float uu[8] = {ua.x, ua.y, ua.z, ua.w, ub.x, ub.y, ub.z, ub.w};
    float ax = 0.f, ay = 0.f, az = 0.f, aw = 0.f;
#pragma unroll
    for (int k = 0; k < 8; ++k) {
      ax = fmaf(uu[k], wreg[k].x, ax);
      ay = fmaf(uu[k], wreg[k].y, ay);
      az = fmaf(uu[k], wreg[k].z, az);
      aw = fmaf(uu[k], wreg[k].w, aw);
    }
    f16x4 st;
    st[0] = (f16)ax; st[1] = (f16)ay; st[2] = (f16)az; st[3] = (f16)aw;
    *(f16x4*)(pbase + (size_t)b * 18432) = st;
  }
}

// ---------------- dynamic routing, one block per (c,b) ---------------------
__device__ __forceinline__ float wave_sum(float v) {
#pragma unroll
  for (int off = 32; off > 0; off >>= 1) v += __shfl_xor(v, off);
  return v;
}
__device__ __forceinline__ float wave_max(float v) {
#pragma unroll
  for (int off = 32; off > 0; off >>= 1) v = fmaxf(v, __shfl_xor(v, off));
  return v;
}

__global__ __launch_bounds__(256, 2) void routing_kernel(
    const f16* __restrict__ Pg, float* __restrict__ caps)
{
  const int c = blockIdx.x >> 9;
  const int b = blockIdx.x & 511;
  const int t = threadIdx.x;
  const int wid = t >> 6;
  const int lane = t & 63;
  __shared__ float xred[4 * 17];

  float P[5][16];
  float lg[5];
  const int nk = (t < 128) ? 5 : 4;
#pragma unroll
  for (int k = 0; k < 5; ++k)
#pragma unroll
    for (int o = 0; o < 16; ++o) P[k][o] = 0.f;

  const f16* pbase = Pg + (size_t)((c * 512 + b) * 1152) * 16;
#pragma unroll
  for (int k = 0; k < 5; ++k) {
    if (k < nk) {
      const int r = t + (k << 8);
      const f16x8 p0 = *(const f16x8*)&pbase[(size_t)r * 16];
      const f16x8 p1 = *(const f16x8*)&pbase[(size_t)r * 16 + 8];
#pragma unroll
      for (int o = 0; o < 8; ++o) {
        P[k][o]     = (float)p0[o];
        P[k][o + 8] = (float)p1[o];
      }
    }
  }

  float v[16];
  {
    float sq = 0.f;
#pragma unroll
    for (int o = 0; o < 16; ++o) {
      float p = 0.f;
#pragma unroll
      for (int k = 0; k < 5; ++k) p += P[k][o];
      p = wave_sum(p);
      if (lane == 0) xred[wid * 17 + o] = p;
      v[o] = 0.f;
    }
    __syncthreads();
#pragma unroll
    for (int o = 0; o < 16; ++o) {
      const float s = (xred[o] + xred[17 + o] + xred[34 + o] + xred[51 + o]) *
                      (1.f / 1152.f);
      v[o] = s;
      sq = fmaf(s, s, sq);
    }
    const float scale = sq / ((1.f + sq) * sqrtf(sq));
#pragma unroll
    for (int o = 0; o < 16; ++o) v[o] *= scale;
    __syncthreads();
  }
#pragma unroll
  for (int k = 0; k < 5; ++k) {
    float a = 0.f;
#pragma unroll
    for (int o = 0; o < 16; ++o) a = fmaf(P[k][o], v[o], a);
    lg[k] = a;
  }

  for (int it = 1; it < 3; ++it) {
    float m = -1e30f;
#pragma unroll
    for (int k = 0; k < 5; ++k) if (k < nk) m = fmaxf(m, lg[k]);
    m = wave_max(m);
    if (lane == 0) xred[wid * 17 + 16] = m;
    __syncthreads();
    const float mx = fmaxf(fmaxf(xred[16], xred[17 + 16]),
                           fmaxf(xred[34 + 16], xred[51 + 16]));
    __syncthreads();
    float e[5];
#pragma unroll
    for (int k = 0; k < 5; ++k) e[k] = (k < nk) ? expf(lg[k] - mx) : 0.f;
    float pS = 0.f;
#pragma unroll
    for (int k = 0; k < 5; ++k) pS += e[k];
    pS = wave_sum(pS);
    if (lane == 0) xred[wid * 17 + 16] = pS;
#pragma unroll
    for (int o = 0; o < 16; ++o) {
      float p = 0.f;
#pragma unroll
      for (int k = 0; k < 5; ++k) p = fmaf(e[k], P[k][o], p);
      p = wave_sum(p);
      if (lane == 0) xred[wid * 17 + o] = p;
    }
    __syncthreads();
    const float S = xred[16] + xred[17 + 16] + xred[34 + 16] + xred[51 + 16];
    const float inv = 1.f / S;
    float sq = 0.f;
#pragma unroll
    for (int o = 0; o < 16; ++o) {
      const float s = (xred[o] + xred[17 + o] + xred[34 + o] + xred[51 + o]) * inv;
      v[o] = s;
      sq = fmaf(s, s, sq);
    }
    const float scale = sq / ((1.f + sq) * sqrtf(sq));
#pragma unroll
    for (int o = 0; o < 16; ++o) v[o] *= scale;
    __syncthreads();
    if (it < 2) {
#pragma unroll
      for (int k = 0; k < 5; ++k) {
        float a = 0.f;
#pragma unroll
        for (int o = 0; o < 16; ++o) a = fmaf(P[k][o], v[o], a);
        lg[k] += a;
      }
    }
  }
  if (t == 0) {
    float* cp = &caps[(b * 10 + c) * 16];
#pragma unroll
    for (int o = 0; o < 16; ++o) cp[o] = v[o];
  }
}

// --------- classes softmax + argmax one-hot mask ---------------------------
__global__ void classes_kernel(const float* __restrict__ caps,
                               float* __restrict__ out_classes,
                               float* __restrict__ d0)
{
  const int b = blockIdx.x * 256 + threadIdx.x;
  if (b >= 512) return;
  float nrm[10];
#pragma unroll
  for (int cc = 0; cc < 10; ++cc) {
    float sq = 0.f;
#pragma unroll
    for (int o = 0; o < 16; ++o) {
      const float vv = caps[(b * 10 + cc) * 16 + o];
      sq = fmaf(vv, vv, sq);
    }
    nrm[cc] = sqrtf(sq);
  }
  float mx = nrm[0]; int cs = 0;
#pragma unroll
  for (int cc = 1; cc < 10; ++cc)
    if (nrm[cc] > mx) { mx = nrm[cc]; cs = cc; }
  float e[10], ssum = 0.f;
#pragma unroll
  for (int cc = 0; cc < 10; ++cc) { e[cc] = expf(nrm[cc] - mx); ssum += e[cc]; }
  const float inv = 1.f / ssum;
#pragma unroll
  for (int cc = 0; cc < 10; ++cc) out_classes[b * 10 + cc] = e[cc] * inv;
#pragma unroll
  for (int cc = 0; cc < 10; ++cc)
#pragma unroll
    for (int o = 0; o < 16; ++o)
      d0[b * 160 + cc * 16 + o] = (cc == cs) ? caps[(b * 10 + cc) * 16 + o] : 0.f;
}

// --------- decoder GEMM: C[M,N] = act(A[M,K] @ W[N,K]^T + bias) ------------
__global__ __launch_bounds__(256, 2) void fc_kernel(
    const float* __restrict__ A, const float* __restrict__ W,
    const float* __restrict__ bias, float* __restrict__ C,
    int N, int K, int act)
{
  __shared__ float As[64][17];
  __shared__ float Ws[64][17];
  const int t = threadIdx.x;
  const int tm = t >> 4, tn = t & 15;
  const int m0 = blockIdx.y << 6, n0 = blockIdx.x << 6;
  const int lr = t >> 2, lq = (t & 3) << 2;
  float acc[4][4] = {};
  for (int k0 = 0; k0 < K; k0 += 16) {
    const float4 av = *(const float4*)&A[(m0 + lr) * K + k0 + lq];
    float4 wv = make_float4(0.f, 0.f, 0.f, 0.f);
    const int wn = n0 + lr;
    if (wn < N) wv = *(const float4*)&W[wn * K + k0 + lq];
    __syncthreads();
    As[lr][lq+0] = av.x; As[lr][lq+1] = av.y; As[lr][lq+2] = av.z; As[lr][lq+3] = av.w;
    Ws[lr][lq+0] = wv.x; Ws[lr][lq+1] = wv.y; Ws[lr][lq+2] = wv.z; Ws[lr][lq+3] = wv.w;
    __syncthreads();
#pragma unroll
    for (int kk = 0; kk < 16; ++kk) {
      float a[4], w[4];
#pragma unroll
      for (int i = 0; i < 4; ++i) a[i] = As[tm * 4 + i][kk];
#pragma unroll
      for (int j = 0; j < 4; ++j) w[j] = Ws[tn * 4 + j][kk];
#pragma unroll
      for (int i = 0; i < 4; ++i)
#pragma unroll
        for (int j = 0; j < 4; ++j) acc[i][j] = fmaf(a[i], w[j], acc[i][j]);
    }
  }
#pragma unroll
  for (int i = 0; i < 4; ++i) {
    const int m = m0 + tm * 4 + i;
#pragma unroll
    for (int j = 0; j < 4; ++j) {
      const int n = n0 + tn * 4 + j;
      if (n < N) {
        float vv = acc[i][j] + bias[n];
        vv = act ? (1.f / (1.f + expf(-vv))) : fmaxf(vv, 0.f);
        C[m * N + n] = vv;
      }
    }
  }
}

// ============================================================================
extern "C" void kernel_launch(void* const* d_in, const int* in_sizes, int n_in,
                              void* d_out, int out_size, void* d_ws, size_t ws_size,
                              hipStream_t stream)
{
  const float* x       = (const float*)d_in[0];
  const float* conv1_w = (const float*)d_in[1];
  const float* conv1_b = (const float*)d_in[2];
  const float* prim_w  = (const float*)d_in[3];
  const float* prim_b  = (const float*)d_in[4];
  const float* route_w = (const float*)d_in[5];
  const float* dec_w1  = (const float*)d_in[6];
  const float* dec_b1  = (const float*)d_in[7];
  const float* dec_w2  = (const float*)d_in[8];
  const float* dec_b2  = (const float*)d_in[9];
  const float* dec_w3  = (const float*)d_in[10];
  const float* dec_b3  = (const float*)d_in[11];
  float* out = (float*)d_out;

  char* ws = (char*)d_ws;
  f16*   ht   = (f16*)(ws);                        // 104,857,600 B
  f16*   wtp  = (f16*)(ws + 104857600);            //  10,616,832 B
  float* part = (float*)(ws + 115474432);          //  75,497,472 B (4 slices)
  float* u    = (float*)(ws + 190971904);          //  18,874,368 B
  f16*   P    = (f16*)(ws);                        // 188,743,680 B (overlays)
  float* caps = (float*)(ws + 209846272);          // 327,680 B
  float* d0   = (float*)(ws + 210173952);          // 327,680 B
  float* d1   = (float*)(ws + 210501632);          // 1,048,576 B
  float* d2   = (float*)(ws + 211550208);          // 2,097,152 B

  hipLaunchKernelGGL(conv1_kernel, dim3(512), dim3(256), 0, stream,
                     x, conv1_w, conv1_b, ht);
  hipLaunchKernelGGL(wtrans_kernel, dim3(256, 4), dim3(256), 0, stream,
                     prim_w, wtp);
  hipLaunchKernelGGL(prim_mfma_kernel, dim3(1152), dim3(256), 0, stream,
                     ht, wtp, part);
  hipLaunchKernelGGL(squash_kernel, dim3(2304), dim3(256), 0, stream,
                     part, prim_b, u);
  hipLaunchKernelGGL(priors_kernel, dim3(18, 8, 10), dim3(256), 0, stream,
                     u, route_w, P);
  hipLaunchKernelGGL(routing_kernel, dim3(5120), dim3(256), 0, stream,
                     P, caps);
  hipLaunchKernelGGL(classes_kernel, dim3(2), dim3(256), 0, stream,
                     caps, out, d0);
  hipLaunchKernelGGL(fc_kernel, dim3(8, 8), dim3(256), 0, stream,
                     d0, dec_w1, dec_b1, d1, 512, 160, 0);
  hipLaunchKernelGGL(fc_kernel, dim3(16, 8), dim3(256), 0, stream,
                     d1, dec_w2, dec_b2, d2, 1024, 512, 0);
  hipLaunchKernelGGL(fc_kernel, dim3(13, 8), dim3(256), 0, stream,
                     d2, dec_w3, dec_b3, out + 5120, 784, 1024, 1);
}